// Round 16
// baseline (101.333 us; speedup 1.0000x reference)
//
#include <hip/hip_runtime.h>
#include <math.h>

// ---------------------------------------------------------------------------
// Problem: B=64 batches. a_p = a@W1^T + b1 [64,1024]; b_p = b@W2^T + b2.
// cost[b,i,j] = (a_p[b,i]-b_p[b,j])^2 ; DTW DP R[i,j]=cost+min(diag,up,left);
// out[b] = R[1023,1023].
// ---------------------------------------------------------------------------

#define L 1024
#define BATCH 64

// ---------------- GEMM: out[b,i] = sum_k X[b,k]*W[i,k] (+ bias) ------------
// Inner loop uses ds_read_b128 (float4) from LDS; pad = 36 floats (9x16B,
// odd) -> conflict-free b128 reads. 5 b128 reads + 16 FMA per 4-k chunk.
__global__ __launch_bounds__(256) void proj_kernel(
    const float* __restrict__ a, const float* __restrict__ b,
    const float* __restrict__ W1, const float* __restrict__ b1,
    const float* __restrict__ W2, const float* __restrict__ b2,
    float* __restrict__ ap, float* __restrict__ bp, int KC) {
  int part = blockIdx.x >> 7;
  int sub = blockIdx.x & 127;
  const float* X;
  const float* W;
  const float* bias;
  float* out;
  int i0;
  if (sub < 64) {
    X = a; W = W1; bias = b1; out = ap + part * BATCH * L; i0 = sub * 16;
  } else {
    X = b; W = W2; bias = b2; out = bp + part * BATCH * L; i0 = (sub - 64) * 16;
  }

  __shared__ float a_s[64][36];
  __shared__ float w_s[16][36];

  int tid = threadIdx.x;
  int lane_b = tid & 63;
  int iq = tid >> 6;

  float acc[4] = {0.f, 0.f, 0.f, 0.f};

  int kbeg = part * KC;
  int kend = kbeg + KC;
  for (int k0 = kbeg; k0 < kend; k0 += 32) {
    {
      int row = tid >> 2;
      int kl = (tid & 3) * 8;
      const float4* src = reinterpret_cast<const float4*>(&X[row * L + k0 + kl]);
      float4 v0 = src[0];
      float4 v1 = src[1];
      *reinterpret_cast<float4*>(&a_s[row][kl]) = v0;
      *reinterpret_cast<float4*>(&a_s[row][kl + 4]) = v1;
    }
    {
      int row = tid >> 4;
      int kl = (tid & 15) * 2;
      float2 v = *reinterpret_cast<const float2*>(&W[(i0 + row) * L + k0 + kl]);
      w_s[row][kl] = v.x;
      w_s[row][kl + 1] = v.y;
    }
    __syncthreads();
    #pragma unroll
    for (int kl = 0; kl < 32; kl += 4) {
      float4 av = *reinterpret_cast<const float4*>(&a_s[lane_b][kl]);
      #pragma unroll
      for (int m = 0; m < 4; ++m) {
        float4 wv = *reinterpret_cast<const float4*>(&w_s[iq * 4 + m][kl]);
        acc[m] += av.x * wv.x + av.y * wv.y + av.z * wv.z + av.w * wv.w;
      }
    }
    __syncthreads();
  }

  #pragma unroll
  for (int m = 0; m < 4; ++m) {
    int i = i0 + iq * 4 + m;
    float bv = (part == 0) ? bias[i] : 0.f;
    out[lane_b * L + i] = acc[m] + bv;
  }
}

// ---------------- DTW: 4 waves/batch, all-DPP LDS-free steady step ---------
// Lane (w,t) owns CPL=4 columns from (w*64+t)*4; delay D = w*OFF + t rows.
// Step s: lane processes row i = s-D. Per-step dataflow, ALL untied
// bound_ctrl=1 DPP (single v_mov_b32_dpp each) + cndmasks; ZERO per-step LDS:
//   shifted = shr_z(right); left = lane0 ? ringchunk : shifted
//   ringchunk = shl_z(ringchunk)
//   apsh = shr_z(apv);     apv  = lane0 ? apchunk : apsh    (ap systolic flow)
//   apchunk = shl_z(apchunk)
//   vprod = shl_z(vprod);  vprod = lane63 ? right : vprod
// Feed-walk safety (bound_ctrl zero-fill): apchunk/ringchunk are reloaded
// every group and only lanes k<KBAR=32 are consumed by lane 0 (zero from
// lane 63 needs 63 walks); apv's lane-0 zero is overwritten by cndmask;
// wave-0 ringchunk re-inits to INF each group (R14 bugfix); skirt ap rows
// are 0 and their cells are PRED-discarded.
// Group = KBAR=32 steps; per group: 1 ds_read (apchunk), 1 exec-masked
// ds_read (ring feed, w>0), 1 exec-masked ds_write (producer flush),
// 1 __syncthreads(). GAP = OFF-63 = 32 = KBAR: production is exactly one
// barrier-ordered group before consumption; slot reuse distance 2 groups.

#define NW 4
#define CPL 4
#define KBAR 32
#define OFF 95                       // 64 + 31 -> GAP = 32
#define DMAX (OFF * (NW - 1) + 63)   // 348
#define NG 43                        // ceil((L + DMAX) / KBAR)
#define NSTEPS (NG * KBAR)           // 1376
#define APPAD (DMAX + NSTEPS + 64)   // 1788

__device__ __forceinline__ float dpp_shr1_z(float v) {
  // wave_shr:1, bound_ctrl=1: lane i <- lane i-1; lane 0 <- 0. One instr.
  int r = __builtin_amdgcn_update_dpp(0, __float_as_int(v), 0x138, 0xf, 0xf,
                                      true);
  return __int_as_float(r);
}

__device__ __forceinline__ float dpp_shl1_z(float v) {
  // wave_shl:1, bound_ctrl=1: lane i <- lane i+1; lane 63 <- 0. One instr.
  int r = __builtin_amdgcn_update_dpp(0, __float_as_int(v), 0x130, 0xf, 0xf,
                                      true);
  return __int_as_float(r);
}

__device__ __forceinline__ float min3f(float x, float y, float z) {
  float r;
  asm("v_min3_f32 %0, %1, %2, %3" : "=v"(r) : "v"(x), "v"(y), "v"(z));
  return r;
}

__global__ __launch_bounds__(256, 1) void dtw_kernel(
    const float* __restrict__ app, const float* __restrict__ bpp,
    float* __restrict__ out, int parts) {
  const int b = blockIdx.x;
  const int tid = threadIdx.x;
  const int w = tid >> 6;
  const int t = tid & 63;
  const int woff = w * OFF;
  const int D = woff + t;
  const float INF = INFINITY;

  __shared__ float ap_pad[APPAD];
  __shared__ float ring[NW - 1][64];

  // ap_pad[DMAX + i] = sum_p ap_part[p][b,i]; zero skirts.
  for (int idx = tid; idx < APPAD; idx += 256) {
    int src = idx - DMAX;
    float v = 0.f;
    if ((unsigned)src < (unsigned)L) {
      v = app[b * L + src];
      for (int p = 1; p < parts; ++p) v += app[p * BATCH * L + b * L + src];
    }
    ap_pad[idx] = v;
  }

  float4 bv = *reinterpret_cast<const float4*>(&bpp[b * L + tid * CPL]);
  for (int p = 1; p < parts; ++p) {
    float4 u = *reinterpret_cast<const float4*>(
        &bpp[p * BATCH * L + b * L + tid * CPL]);
    bv.x += u.x; bv.y += u.y; bv.z += u.z; bv.w += u.w;
  }
  const float bpv0 = bv.x, bpv1 = bv.y, bpv2 = bv.z, bpv3 = bv.w;

  float p0 = INF, p1 = INF, p2 = INF, p3 = INF;  // prev-row cells
  float right = INF, prev_left = INF;
  float vprod = INF;
  float ringchunk = INF;  // set per group below
  float apv = 0.f;        // systolic ap value (row s-D), flows lane->lane
  float apchunk = 0.f;    // per-group ap feed for lane 0 (walks via shl)
  const bool lane0 = (t == 0);
  const bool lane63 = (t == 63);
  // apchunk lane k (group at s0) holds ap row s0+k-woff:
  const int ap_base = DMAX - woff + t;

  __syncthreads();

  // One 32-step group. PRED: row-range predicate (ramp/drain). FIRSTG: the
  // first group seeds R[0,0]'s left and carries the one-time diag fixup.
#define DTW_GROUP(s0v, PRED, FIRSTG)                                         \
  {                                                                          \
    const int s0 = (s0v);                                                    \
    apchunk = ap_pad[ap_base + s0];                                          \
    if (w == 0)                                                              \
      ringchunk = ((FIRSTG) && lane0) ? 0.f : INF;                           \
    else if (t < KBAR)                                                       \
      ringchunk = ring[w - 1][(s0 - woff + t) & 63];                         \
    _Pragma("unroll")                                                        \
    for (int k = 0; k < KBAR; ++k) {                                         \
      float shifted = dpp_shr1_z(right);                                     \
      float left = lane0 ? ringchunk : shifted;                              \
      ringchunk = dpp_shl1_z(ringchunk);                                     \
      float apsh = dpp_shr1_z(apv);                                          \
      apv = lane0 ? apchunk : apsh;                                          \
      apchunk = dpp_shl1_z(apchunk);                                         \
      int ii = s0 + k - D;                                                   \
      if (!(PRED) || ((unsigned)ii < (unsigned)L)) {                         \
        float dprev = prev_left;                                             \
        if ((FIRSTG) && k == 1 && w == 0 && t == 0) dprev = INF;             \
        prev_left = left;                                                    \
        float d0 = apv - bpv0, d1 = apv - bpv1;                              \
        float d2 = apv - bpv2, d3 = apv - bpv3;                              \
        float x = left, bb;                                                  \
        bb = min3f(p0, dprev, x); x = __builtin_fmaf(d0, d0, bb);            \
        dprev = p0; p0 = x;                                                  \
        bb = min3f(p1, dprev, x); x = __builtin_fmaf(d1, d1, bb);            \
        dprev = p1; p1 = x;                                                  \
        bb = min3f(p2, dprev, x); x = __builtin_fmaf(d2, d2, bb);            \
        dprev = p2; p2 = x;                                                  \
        bb = min3f(p3, dprev, x); x = __builtin_fmaf(d3, d3, bb);            \
        p3 = x;                                                              \
        right = x;                                                           \
      }                                                                      \
      vprod = dpp_shl1_z(vprod);                                             \
      vprod = lane63 ? right : vprod;                                        \
    }                                                                        \
    if (w < NW - 1 && t >= 64 - KBAR)                                        \
      ring[w][(s0 + t - woff - (63 + KBAR)) & 63] = vprod;                   \
    __syncthreads();                                                         \
  }

  // Ramp: groups 0..10 (steps 0..351 cover s < DMAX=348, predicated).
  for (int g = 0; g < 11; ++g) DTW_GROUP(g * KBAR, true, g == 0);
  // Steady: groups 11..31 (steps 352..1023; every lane's i in [0,L)).
  for (int g = 11; g < 32; ++g) DTW_GROUP(g * KBAR, false, false);
  // Drain: groups 32..42 (steps 1024..1375; last active step 1371).
  for (int g = 32; g < NG; ++g) DTW_GROUP(g * KBAR, true, false);
#undef DTW_GROUP

  if (tid == NW * 64 - 1) out[b] = right;  // R[1023,1023]
}

extern "C" void kernel_launch(void* const* d_in, const int* in_sizes, int n_in,
                              void* d_out, int out_size, void* d_ws, size_t ws_size,
                              hipStream_t stream) {
  const float* a  = (const float*)d_in[0];
  const float* b  = (const float*)d_in[1];
  const float* W1 = (const float*)d_in[2];
  const float* b1 = (const float*)d_in[3];
  const float* W2 = (const float*)d_in[4];
  const float* b2 = (const float*)d_in[5];
  float* out = (float*)d_out;

  size_t per_part = (size_t)2 * BATCH * L * sizeof(float);
  int parts = 1;
  if (ws_size >= 4 * per_part) parts = 4;
  else if (ws_size >= 2 * per_part) parts = 2;

  float* ap = (float*)d_ws;                    // parts x [BATCH, L]
  float* bp = ap + (size_t)parts * BATCH * L;  // parts x [BATCH, L]

  proj_kernel<<<128 * parts, 256, 0, stream>>>(a, b, W1, b1, W2, b2,
                                               ap, bp, L / parts);
  dtw_kernel<<<BATCH, 256, 0, stream>>>(ap, bp, out, parts);
}